// Round 16
// baseline (233.459 us; speedup 1.0000x reference)
//
#include <hip/hip_runtime.h>

// GAT layer, CSR + single-pass softmax + MFMA linear. N=100000, E=1.6M, DIN=128, H=4, D=16.
// ROUND 16 = R14 blessed k_linear geometry (782 blocks x 512 thr, 1 tile) with
// the LDS weight staging DELETED: k_wprep builds the pre-transposed bf16
// fragment table (21.76 KB) in global once; waves load fragments directly
// (L1-resident). No barrier in k_linear. Everything else = R15.

#define DIN 128
#define HD  64
#define NH  4
#define BTP 136

typedef __attribute__((ext_vector_type(8))) short short8;
typedef __attribute__((ext_vector_type(4))) float f32x4;

__device__ __forceinline__ float leaky02(float v) { return v > 0.f ? v : 0.2f * v; }

__device__ __forceinline__ float bf2f(unsigned short u) {
  union { unsigned u32; float f; } c; c.u32 = ((unsigned)u) << 16; return c.f;
}
__device__ __forceinline__ unsigned short f2bf(float f) {
  union { float f; unsigned u; } c; c.f = f;
  unsigned r = c.u + 0x7FFFu + ((c.u >> 16) & 1u);  // RNE
  return (unsigned short)(r >> 16);
}
__device__ __forceinline__ unsigned cvt_pk_bf16(float lo, float hi) {
  unsigned r;
  asm("v_cvt_pk_bf16_f32 %0, %1, %2" : "=v"(r) : "v"(lo), "v"(hi));
  return r;  // low16 = bf16(lo), high16 = bf16(hi)
}

// ---------------- K0: build pre-transposed bf16 fragment table ----------------
// btg[c*BTP + k]: c<64 -> bf16(Wlin[k][c]); 64..71 -> wfold; else 0.
// Byte-identical values to the previous inline staging.
__global__ void k_wprep(const float* __restrict__ Wlin, const float* __restrict__ Watt,
                        unsigned short* __restrict__ btg) {
  for (int i = threadIdx.x; i < 80 * BTP; i += 256) {
    const int c = i / BTP, k = i % BTP;
    unsigned short v = 0;
    if (k < DIN) {
      if (c < 64) {
        v = f2bf(Wlin[k * HD + c]);
      } else if (c < 72) {
        const int cc = c - 64;
        const int head = cc & 3, dsth = (cc >= 4) ? 16 : 0;
        float s = 0.f;
#pragma unroll
        for (int d = 0; d < 16; ++d)
          s += Wlin[k * HD + head * 16 + d] * Watt[head * 32 + dsth + d];
        v = f2bf(s);
      }
    }
    btg[i] = v;
  }
}

// ---------------- K1: MFMA linear, fragments direct from global, no barrier ----------------
// Block: 512 thr (8 waves), 128 rows (8 waves x 16 rows). R9-R14 blessed geometry.
__global__ __launch_bounds__(512)
void k_linear(const float* __restrict__ x,
              const unsigned short* __restrict__ btg,
              unsigned short* __restrict__ hb,
              float* __restrict__ a_src, float* __restrict__ a_dst,
              int N,
              const int* __restrict__ ei, int* __restrict__ deg, int E) {
  __shared__ __align__(16) unsigned short OT[8][16 * 68]; // 17 KiB C-staging (pad 68)
  __shared__ __align__(16) float AT[8][16 * 8];           // 4 KiB att-staging
  const int tid = threadIdx.x;
  const int lane = tid & 63;
  const int wid  = tid >> 6;  // 0..7

  const int row0 = blockIdx.x * 128 + wid * 16;
  const bool rowok = row0 < N;

  // x loads first: HBM latency overlaps fragment loads
  float4 xv[8];
  if (rowok) {
    const int r = min(row0 + (lane & 15), N - 1);
    const float* xp = x + (size_t)r * DIN + ((lane >> 4) * 8);
#pragma unroll
    for (int kt = 0; kt < 4; ++kt) {
      xv[kt * 2 + 0] = *(const float4*)(xp + kt * 32);
      xv[kt * 2 + 1] = *(const float4*)(xp + kt * 32 + 4);
    }
  }

  // B fragments direct from global (21.76 KB table, L1-resident per CU)
  short8 bf[5][4];
#pragma unroll
  for (int ct = 0; ct < 5; ++ct) {
    const int c = (ct < 4) ? (ct * 16 + (lane & 15)) : (64 + (lane & 15));
#pragma unroll
    for (int kt = 0; kt < 4; ++kt)
      bf[ct][kt] = *(const short8*)(&btg[c * BTP + kt * 32 + (lane >> 4) * 8]);
  }

  if (rowok) {
    short8 af[4];
#pragma unroll
    for (int kt = 0; kt < 4; ++kt) {
      unsigned* ap = (unsigned*)&af[kt];
      const float4 a = xv[kt * 2], b = xv[kt * 2 + 1];
      ap[0] = cvt_pk_bf16(a.x, a.y);
      ap[1] = cvt_pk_bf16(a.z, a.w);
      ap[2] = cvt_pk_bf16(b.x, b.y);
      ap[3] = cvt_pk_bf16(b.z, b.w);
    }
    f32x4 acc[5] = {{0,0,0,0},{0,0,0,0},{0,0,0,0},{0,0,0,0},{0,0,0,0}};
#pragma unroll
    for (int ct = 0; ct < 5; ++ct)
#pragma unroll
      for (int kt = 0; kt < 4; ++kt)
        acc[ct] = __builtin_amdgcn_mfma_f32_16x16x32_bf16(af[kt], bf[ct][kt], acc[ct], 0, 0, 0);

    // --- LDS-staged epilogue (wave-private, no barrier) ---
    // C/D layout: col = lane&15, row = (lane>>4)*4 + j
    const int c0 = lane & 15;
    const int r0 = (lane >> 4) * 4;
#pragma unroll
    for (int j = 0; j < 4; ++j) {
#pragma unroll
      for (int ct = 0; ct < 4; ++ct)
        OT[wid][(r0 + j) * 68 + ct * 16 + c0] = f2bf(acc[ct][j]);
      if (c0 < 8) AT[wid][(r0 + j) * 8 + c0] = acc[4][j];
    }
    // coalesced writeback: 2 rows (256B) per instruction
    unsigned* hbu = (unsigned*)(hb + (size_t)row0 * HD);
#pragma unroll
    for (int it = 0; it < 8; ++it) {
      const int rr = it * 2 + (lane >> 5);
      const int cw = lane & 31;
      const unsigned v = *(const unsigned*)&OT[wid][rr * 68 + cw * 2];
      if (row0 + rr < N) hbu[rr * 32 + cw] = v;
    }
    {
      const int rr = lane >> 2, cc = lane & 3;
      if (row0 + rr < N) {
        a_src[(row0 + rr) * 4 + cc] = AT[wid][rr * 8 + cc];
        a_dst[(row0 + rr) * 4 + cc] = AT[wid][rr * 8 + 4 + cc];
      }
    }
  }

  // fused degree histogram over this block's edge slice
  const int per = (E + gridDim.x - 1) / gridDim.x;
  const int e0 = blockIdx.x * per;
  const int e1 = min(e0 + per, E);
  for (int e = e0 + tid; e < e1; e += 512)
    atomicAdd(&deg[ei[e]], 1);
}

// ---------------- K3a: per-block exclusive scan ----------------
__global__ void k_scanA(const int* __restrict__ deg, int* __restrict__ offs,
                        int* __restrict__ partials, int N) {
  __shared__ int wsum[16];
  const int tid = threadIdx.x, lane = tid & 63, wv = tid >> 6;
  int i = blockIdx.x * 1024 + tid;
  int v = (i < N) ? deg[i] : 0;
  int sc = v;
#pragma unroll
  for (int s = 1; s < 64; s <<= 1) {
    int t = __shfl_up(sc, s, 64);
    if (lane >= s) sc += t;
  }
  if (lane == 63) wsum[wv] = sc;
  __syncthreads();
  if (wv == 0 && lane < 16) {
    int w = wsum[lane];
    int s2 = w;
#pragma unroll
    for (int s = 1; s < 16; s <<= 1) {
      int t = __shfl_up(s2, s, 64);
      if (lane >= s) s2 += t;
    }
    wsum[lane] = s2 - w;
  }
  __syncthreads();
  int excl = sc - v + wsum[wv];
  if (i < N) offs[i] = excl;
  if (tid == 1023) partials[blockIdx.x] = excl + v;
}

// ---------------- K3b: add block bases ----------------
__global__ void k_scanB(int* __restrict__ offs, const int* __restrict__ partials, int N) {
  __shared__ int sbase;
  const int tid = threadIdx.x, b = blockIdx.x;
  if (tid < 64) {
    int acc = 0;
    for (int j = tid; j < b; j += 64) acc += partials[j];
#pragma unroll
    for (int s = 32; s >= 1; s >>= 1) acc += __shfl_xor(acc, s, 64);
    if (tid == 0) sbase = acc;
  }
  __syncthreads();
  int i = b * 1024 + tid;
  if (i < N) offs[i] += sbase;
}

// ---------------- K4: XCD-aware CSR scatter, single dispatch ----------------
__global__ void k_scatter8(const int* __restrict__ ei, int* __restrict__ offs,
                           int* __restrict__ csr, int E, int N) {
  const int xcd  = blockIdx.x & 7;
  const int grp  = blockIdx.x >> 3;
  const int ngrp = gridDim.x >> 3;
  const int step = (N + 7) >> 3;
  const int lo = xcd * step, hi = min(N, lo + step);
  const int stride = ngrp * blockDim.x;
  for (int e = grp * blockDim.x + threadIdx.x; e < E; e += stride) {
    int s = ei[e];
    if (s >= lo && s < hi) {
      int d = ei[E + e];
      int p = atomicAdd(&offs[s], 1);
      csr[p] = d;
    }
  }
}

// ---------------- K5: aggregate, scalarized serial loop ----------------
__global__ __launch_bounds__(256)
void k_agg(const int* __restrict__ offs_end, const int* __restrict__ deg,
           const int* __restrict__ csr, const float4* __restrict__ a_src4,
           const float4* __restrict__ a_dst4,
           const unsigned short* __restrict__ hb,
           float* __restrict__ out, int N) {
  __shared__ float als[4][64 * NH];
  const int lane = threadIdx.x & 63;
  const int wid  = threadIdx.x >> 6;
  const int hh = lane >> 4;
  const int wstride = gridDim.x * 4;

  for (int n0 = blockIdx.x * 4 + wid; n0 < N; n0 += wstride) {
    const int n   = __builtin_amdgcn_readfirstlane(n0);
    const int end = __builtin_amdgcn_readfirstlane(offs_end[n]);
    const int dg  = __builtin_amdgcn_readfirstlane(deg[n]);
    const int beg = end - dg;
    const float4 asv = a_src4[n];

    float s0 = 0.f, s1 = 0.f, s2 = 0.f, s3 = 0.f;
    float acc0 = 0.f, acc1 = 0.f;
    for (int base = beg; base < end; base += 64) {
      const int cnt = __builtin_amdgcn_readfirstlane(min(64, end - base));
      const bool act = lane < cnt;
      const int d = csr[act ? base + lane : beg];
      const float4 ad = a_dst4[d];
      const float p0 = act ? __expf(leaky02(asv.x + ad.x)) : 0.f;
      const float p1 = act ? __expf(leaky02(asv.y + ad.y)) : 0.f;
      const float p2 = act ? __expf(leaky02(asv.z + ad.z)) : 0.f;
      const float p3 = act ? __expf(leaky02(asv.w + ad.w)) : 0.f;
      s0 += p0; s1 += p1; s2 += p2; s3 += p3;
      *(float4*)&als[wid][lane * 4] = make_float4(p0, p1, p2, p3);

      int j = 0;
      for (; j + 8 <= cnt; j += 8) {  // scalar row bases, 8 gathers in flight
        int dds[8];
#pragma unroll
        for (int u = 0; u < 8; ++u)
          dds[u] = __builtin_amdgcn_readfirstlane(csr[base + j + u]);
        float hv[8];
#pragma unroll
        for (int u = 0; u < 8; ++u) hv[u] = bf2f(hb[(size_t)dds[u] * HD + lane]);
#pragma unroll
        for (int u = 0; u < 8; ++u) {
          const float av = als[wid][(j + u) * 4 + hh];
          if (u & 1) acc1 = fmaf(av, hv[u], acc1);
          else       acc0 = fmaf(av, hv[u], acc0);
        }
      }
      for (; j < cnt; ++j) {
        const int dd_ = __builtin_amdgcn_readfirstlane(csr[base + j]);
        const float av = als[wid][j * 4 + hh];
        acc0 = fmaf(av, bf2f(hb[(size_t)dd_ * HD + lane]), acc0);
      }
    }
#pragma unroll
    for (int s = 1; s < 64; s <<= 1) {
      s0 += __shfl_xor(s0, s, 64); s1 += __shfl_xor(s1, s, 64);
      s2 += __shfl_xor(s2, s, 64); s3 += __shfl_xor(s3, s, 64);
    }
    const float sh = (hh == 0) ? s0 : (hh == 1) ? s1 : (hh == 2) ? s2 : s3;
    out[(size_t)n * HD + lane] = (acc0 + acc1) * (1.f / (sh + 1e-16f));
  }
}

extern "C" void kernel_launch(void* const* d_in, const int* in_sizes, int n_in,
                              void* d_out, int out_size, void* d_ws, size_t ws_size,
                              hipStream_t stream) {
  const float* x    = (const float*)d_in[0];
  const int*   ei   = (const int*)d_in[1];
  const float* Wlin = (const float*)d_in[2];
  const float* Watt = (const float*)d_in[3];
  float* out = (float*)d_out;

  const int N = in_sizes[0] / DIN;
  const int E = in_sizes[1] / 2;

  char* ws = (char*)d_ws;
  size_t off = 0;
  auto align16 = [&off]() { off = (off + 15) & ~(size_t)15; };
  unsigned short* hb = (unsigned short*)(ws + off); off += (size_t)N * HD * sizeof(unsigned short); align16();
  float* a_src  = (float*)(ws + off); off += (size_t)N * NH * sizeof(float); align16();
  float* a_dst  = (float*)(ws + off); off += (size_t)N * NH * sizeof(float); align16();
  int*   deg    = (int*)(ws + off);   off += (size_t)N * sizeof(int); align16();
  int*   offs   = (int*)(ws + off);   off += ((size_t)N + 1) * sizeof(int); align16();
  int*   csr    = (int*)(ws + off);   off += (size_t)E * sizeof(int); align16();
  int*   parts  = (int*)(ws + off);   off += 128 * sizeof(int); align16();
  unsigned short* btg = (unsigned short*)(ws + off); off += 80 * BTP * sizeof(unsigned short); align16();

  hipMemsetAsync(deg, 0, (size_t)N * sizeof(int), stream);

  hipLaunchKernelGGL(k_wprep, dim3(1), dim3(256), 0, stream, Wlin, Watt, btg);

  hipLaunchKernelGGL(k_linear, dim3((N + 127) / 128), dim3(512), 0, stream,
                     x, btg, hb, a_src, a_dst, N, ei, deg, E);

  const int SB = (N + 1023) / 1024;
  hipLaunchKernelGGL(k_scanA, dim3(SB), dim3(1024), 0, stream, deg, offs, parts, N);
  hipLaunchKernelGGL(k_scanB, dim3(SB), dim3(1024), 0, stream, offs, parts, N);

  hipLaunchKernelGGL(k_scatter8, dim3(2048), dim3(256), 0, stream,
                     ei, offs, csr, E, N);

  // offs[n] == segment end now
  hipLaunchKernelGGL(k_agg, dim3(4096), dim3(256), 0, stream,
                     offs, deg, csr, (const float4*)a_src, (const float4*)a_dst, hb, out, N);
}

// Round 17
// 196.389 us; speedup vs baseline: 1.1888x; 1.1888x over previous
//
#include <hip/hip_runtime.h>

// GAT layer, CSR + single-pass softmax + MFMA linear. N=100000, E=1.6M, DIN=128, H=4, D=16.
// ROUND 17 = R16 + atomic-diet CSR build:
//   k_hist_rank: rank[e] = atomicAdd(&deg[s],1)  (only remaining atomics)
//   scan -> offs = segment STARTS (never mutated)
//   k_place8  : csr[offs[s]+rank[e]] = d  -- ZERO atomics, XCD-bucketed stores
//   k_agg     : beg = offs[n], end = beg+deg[n]
//   k_linear  : pure MFMA GEMM (hist removed)

#define DIN 128
#define HD  64
#define NH  4
#define BTP 136

typedef __attribute__((ext_vector_type(8))) short short8;
typedef __attribute__((ext_vector_type(4))) float f32x4;

__device__ __forceinline__ float leaky02(float v) { return v > 0.f ? v : 0.2f * v; }

__device__ __forceinline__ float bf2f(unsigned short u) {
  union { unsigned u32; float f; } c; c.u32 = ((unsigned)u) << 16; return c.f;
}
__device__ __forceinline__ unsigned short f2bf(float f) {
  union { float f; unsigned u; } c; c.f = f;
  unsigned r = c.u + 0x7FFFu + ((c.u >> 16) & 1u);  // RNE
  return (unsigned short)(r >> 16);
}
__device__ __forceinline__ unsigned cvt_pk_bf16(float lo, float hi) {
  unsigned r;
  asm("v_cvt_pk_bf16_f32 %0, %1, %2" : "=v"(r) : "v"(lo), "v"(hi));
  return r;  // low16 = bf16(lo), high16 = bf16(hi)
}

// ---------------- K0: build pre-transposed bf16 fragment table ----------------
__global__ void k_wprep(const float* __restrict__ Wlin, const float* __restrict__ Watt,
                        unsigned short* __restrict__ btg) {
  for (int i = threadIdx.x; i < 80 * BTP; i += 256) {
    const int c = i / BTP, k = i % BTP;
    unsigned short v = 0;
    if (k < DIN) {
      if (c < 64) {
        v = f2bf(Wlin[k * HD + c]);
      } else if (c < 72) {
        const int cc = c - 64;
        const int head = cc & 3, dsth = (cc >= 4) ? 16 : 0;
        float s = 0.f;
#pragma unroll
        for (int d = 0; d < 16; ++d)
          s += Wlin[k * HD + head * 16 + d] * Watt[head * 32 + dsth + d];
        v = f2bf(s);
      }
    }
    btg[i] = v;
  }
}

// ---------------- K1: MFMA linear, pure GEMM (no hist) ----------------
// Block: 512 thr (8 waves), 128 rows (8 waves x 16 rows). R9-R16 blessed geometry.
__global__ __launch_bounds__(512)
void k_linear(const float* __restrict__ x,
              const unsigned short* __restrict__ btg,
              unsigned short* __restrict__ hb,
              float* __restrict__ a_src, float* __restrict__ a_dst,
              int N) {
  __shared__ __align__(16) unsigned short OT[8][16 * 68]; // 17 KiB C-staging (pad 68)
  __shared__ __align__(16) float AT[8][16 * 8];           // 4 KiB att-staging
  const int tid = threadIdx.x;
  const int lane = tid & 63;
  const int wid  = tid >> 6;  // 0..7

  const int row0 = blockIdx.x * 128 + wid * 16;
  if (row0 >= N) return;

  // x loads first: HBM latency overlaps fragment loads
  float4 xv[8];
  {
    const int r = min(row0 + (lane & 15), N - 1);
    const float* xp = x + (size_t)r * DIN + ((lane >> 4) * 8);
#pragma unroll
    for (int kt = 0; kt < 4; ++kt) {
      xv[kt * 2 + 0] = *(const float4*)(xp + kt * 32);
      xv[kt * 2 + 1] = *(const float4*)(xp + kt * 32 + 4);
    }
  }

  // B fragments direct from global (21.76 KB table, L1-resident per CU)
  short8 bf[5][4];
#pragma unroll
  for (int ct = 0; ct < 5; ++ct) {
    const int c = (ct < 4) ? (ct * 16 + (lane & 15)) : (64 + (lane & 15));
#pragma unroll
    for (int kt = 0; kt < 4; ++kt)
      bf[ct][kt] = *(const short8*)(&btg[c * BTP + kt * 32 + (lane >> 4) * 8]);
  }

  short8 af[4];
#pragma unroll
  for (int kt = 0; kt < 4; ++kt) {
    unsigned* ap = (unsigned*)&af[kt];
    const float4 a = xv[kt * 2], b = xv[kt * 2 + 1];
    ap[0] = cvt_pk_bf16(a.x, a.y);
    ap[1] = cvt_pk_bf16(a.z, a.w);
    ap[2] = cvt_pk_bf16(b.x, b.y);
    ap[3] = cvt_pk_bf16(b.z, b.w);
  }
  f32x4 acc[5] = {{0,0,0,0},{0,0,0,0},{0,0,0,0},{0,0,0,0},{0,0,0,0}};
#pragma unroll
  for (int ct = 0; ct < 5; ++ct)
#pragma unroll
    for (int kt = 0; kt < 4; ++kt)
      acc[ct] = __builtin_amdgcn_mfma_f32_16x16x32_bf16(af[kt], bf[ct][kt], acc[ct], 0, 0, 0);

  // --- LDS-staged epilogue (wave-private, no barrier) ---
  // C/D layout: col = lane&15, row = (lane>>4)*4 + j
  const int c0 = lane & 15;
  const int r0 = (lane >> 4) * 4;
#pragma unroll
  for (int j = 0; j < 4; ++j) {
#pragma unroll
    for (int ct = 0; ct < 4; ++ct)
      OT[wid][(r0 + j) * 68 + ct * 16 + c0] = f2bf(acc[ct][j]);
    if (c0 < 8) AT[wid][(r0 + j) * 8 + c0] = acc[4][j];
  }
  // coalesced writeback: 2 rows (256B) per instruction
  unsigned* hbu = (unsigned*)(hb + (size_t)row0 * HD);
#pragma unroll
  for (int it = 0; it < 8; ++it) {
    const int rr = it * 2 + (lane >> 5);
    const int cw = lane & 31;
    const unsigned v = *(const unsigned*)&OT[wid][rr * 68 + cw * 2];
    if (row0 + rr < N) hbu[rr * 32 + cw] = v;
  }
  {
    const int rr = lane >> 2, cc = lane & 3;
    if (row0 + rr < N) {
      a_src[(row0 + rr) * 4 + cc] = AT[wid][rr * 8 + cc];
      a_dst[(row0 + rr) * 4 + cc] = AT[wid][rr * 8 + 4 + cc];
    }
  }
}

// ---------------- K2: histogram + per-edge rank (the only atomics left) ----------------
__global__ void k_hist_rank(const int* __restrict__ ei, int* __restrict__ deg,
                            int* __restrict__ rank, int E) {
  int stride = gridDim.x * blockDim.x;
  for (int e = blockIdx.x * blockDim.x + threadIdx.x; e < E; e += stride)
    rank[e] = atomicAdd(&deg[ei[e]], 1);
}

// ---------------- K3a: per-block exclusive scan ----------------
__global__ void k_scanA(const int* __restrict__ deg, int* __restrict__ offs,
                        int* __restrict__ partials, int N) {
  __shared__ int wsum[16];
  const int tid = threadIdx.x, lane = tid & 63, wv = tid >> 6;
  int i = blockIdx.x * 1024 + tid;
  int v = (i < N) ? deg[i] : 0;
  int sc = v;
#pragma unroll
  for (int s = 1; s < 64; s <<= 1) {
    int t = __shfl_up(sc, s, 64);
    if (lane >= s) sc += t;
  }
  if (lane == 63) wsum[wv] = sc;
  __syncthreads();
  if (wv == 0 && lane < 16) {
    int w = wsum[lane];
    int s2 = w;
#pragma unroll
    for (int s = 1; s < 16; s <<= 1) {
      int t = __shfl_up(s2, s, 64);
      if (lane >= s) s2 += t;
    }
    wsum[lane] = s2 - w;
  }
  __syncthreads();
  int excl = sc - v + wsum[wv];
  if (i < N) offs[i] = excl;
  if (tid == 1023) partials[blockIdx.x] = excl + v;
}

// ---------------- K3b: add block bases ----------------
__global__ void k_scanB(int* __restrict__ offs, const int* __restrict__ partials, int N) {
  __shared__ int sbase;
  const int tid = threadIdx.x, b = blockIdx.x;
  if (tid < 64) {
    int acc = 0;
    for (int j = tid; j < b; j += 64) acc += partials[j];
#pragma unroll
    for (int s = 32; s >= 1; s >>= 1) acc += __shfl_xor(acc, s, 64);
    if (tid == 0) sbase = acc;
  }
  __syncthreads();
  int i = b * 1024 + tid;
  if (i < N) offs[i] += sbase;
}

// ---------------- K4: atomic-free placement, XCD-bucketed ----------------
__global__ void k_place8(const int* __restrict__ ei, const int* __restrict__ offs,
                         const int* __restrict__ rank, int* __restrict__ csr,
                         int E, int N) {
  const int xcd  = blockIdx.x & 7;
  const int grp  = blockIdx.x >> 3;
  const int ngrp = gridDim.x >> 3;
  const int step = (N + 7) >> 3;
  const int lo = xcd * step, hi = min(N, lo + step);
  const int stride = ngrp * blockDim.x;
  for (int e = grp * blockDim.x + threadIdx.x; e < E; e += stride) {
    int s = ei[e];
    if (s >= lo && s < hi)
      csr[offs[s] + rank[e]] = ei[E + e];
  }
}

// ---------------- K5: aggregate (beg = start, end = beg + deg) ----------------
__global__ __launch_bounds__(256)
void k_agg(const int* __restrict__ offs_start, const int* __restrict__ deg,
           const int* __restrict__ csr, const float4* __restrict__ a_src4,
           const float4* __restrict__ a_dst4,
           const unsigned short* __restrict__ hb,
           float* __restrict__ out, int N) {
  __shared__ float als[4][64 * NH];
  const int lane = threadIdx.x & 63;
  const int wid  = threadIdx.x >> 6;
  const int hh = lane >> 4;
  const int wstride = gridDim.x * 4;

  for (int n0 = blockIdx.x * 4 + wid; n0 < N; n0 += wstride) {
    const int n   = __builtin_amdgcn_readfirstlane(n0);
    const int beg = __builtin_amdgcn_readfirstlane(offs_start[n]);
    const int dg  = __builtin_amdgcn_readfirstlane(deg[n]);
    const int end = beg + dg;
    const float4 asv = a_src4[n];

    float s0 = 0.f, s1 = 0.f, s2 = 0.f, s3 = 0.f;
    float acc0 = 0.f, acc1 = 0.f;
    for (int base = beg; base < end; base += 64) {
      const int cnt = __builtin_amdgcn_readfirstlane(min(64, end - base));
      const bool act = lane < cnt;
      const int d = csr[act ? base + lane : beg];
      const float4 ad = a_dst4[d];
      const float p0 = act ? __expf(leaky02(asv.x + ad.x)) : 0.f;
      const float p1 = act ? __expf(leaky02(asv.y + ad.y)) : 0.f;
      const float p2 = act ? __expf(leaky02(asv.z + ad.z)) : 0.f;
      const float p3 = act ? __expf(leaky02(asv.w + ad.w)) : 0.f;
      s0 += p0; s1 += p1; s2 += p2; s3 += p3;
      *(float4*)&als[wid][lane * 4] = make_float4(p0, p1, p2, p3);

      int j = 0;
      for (; j + 8 <= cnt; j += 8) {  // scalar row bases, 8 gathers in flight
        int dds[8];
#pragma unroll
        for (int u = 0; u < 8; ++u)
          dds[u] = __builtin_amdgcn_readfirstlane(csr[base + j + u]);
        float hv[8];
#pragma unroll
        for (int u = 0; u < 8; ++u) hv[u] = bf2f(hb[(size_t)dds[u] * HD + lane]);
#pragma unroll
        for (int u = 0; u < 8; ++u) {
          const float av = als[wid][(j + u) * 4 + hh];
          if (u & 1) acc1 = fmaf(av, hv[u], acc1);
          else       acc0 = fmaf(av, hv[u], acc0);
        }
      }
      for (; j < cnt; ++j) {
        const int dd_ = __builtin_amdgcn_readfirstlane(csr[base + j]);
        const float av = als[wid][j * 4 + hh];
        acc0 = fmaf(av, bf2f(hb[(size_t)dd_ * HD + lane]), acc0);
      }
    }
#pragma unroll
    for (int s = 1; s < 64; s <<= 1) {
      s0 += __shfl_xor(s0, s, 64); s1 += __shfl_xor(s1, s, 64);
      s2 += __shfl_xor(s2, s, 64); s3 += __shfl_xor(s3, s, 64);
    }
    const float sh = (hh == 0) ? s0 : (hh == 1) ? s1 : (hh == 2) ? s2 : s3;
    out[(size_t)n * HD + lane] = (acc0 + acc1) * (1.f / (sh + 1e-16f));
  }
}

extern "C" void kernel_launch(void* const* d_in, const int* in_sizes, int n_in,
                              void* d_out, int out_size, void* d_ws, size_t ws_size,
                              hipStream_t stream) {
  const float* x    = (const float*)d_in[0];
  const int*   ei   = (const int*)d_in[1];
  const float* Wlin = (const float*)d_in[2];
  const float* Watt = (const float*)d_in[3];
  float* out = (float*)d_out;

  const int N = in_sizes[0] / DIN;
  const int E = in_sizes[1] / 2;

  char* ws = (char*)d_ws;
  size_t off = 0;
  auto align16 = [&off]() { off = (off + 15) & ~(size_t)15; };
  unsigned short* hb = (unsigned short*)(ws + off); off += (size_t)N * HD * sizeof(unsigned short); align16();
  float* a_src  = (float*)(ws + off); off += (size_t)N * NH * sizeof(float); align16();
  float* a_dst  = (float*)(ws + off); off += (size_t)N * NH * sizeof(float); align16();
  int*   deg    = (int*)(ws + off);   off += (size_t)N * sizeof(int); align16();
  int*   offs   = (int*)(ws + off);   off += ((size_t)N + 1) * sizeof(int); align16();
  int*   csr    = (int*)(ws + off);   off += (size_t)E * sizeof(int); align16();
  int*   rank   = (int*)(ws + off);   off += (size_t)E * sizeof(int); align16();
  int*   parts  = (int*)(ws + off);   off += 128 * sizeof(int); align16();
  unsigned short* btg = (unsigned short*)(ws + off); off += 80 * BTP * sizeof(unsigned short); align16();

  hipMemsetAsync(deg, 0, (size_t)N * sizeof(int), stream);

  hipLaunchKernelGGL(k_wprep, dim3(1), dim3(256), 0, stream, Wlin, Watt, btg);

  hipLaunchKernelGGL(k_linear, dim3((N + 127) / 128), dim3(512), 0, stream,
                     x, btg, hb, a_src, a_dst, N);

  hipLaunchKernelGGL(k_hist_rank, dim3(2048), dim3(256), 0, stream, ei, deg, rank, E);

  const int SB = (N + 1023) / 1024;
  hipLaunchKernelGGL(k_scanA, dim3(SB), dim3(1024), 0, stream, deg, offs, parts, N);
  hipLaunchKernelGGL(k_scanB, dim3(SB), dim3(1024), 0, stream, offs, parts, N);

  hipLaunchKernelGGL(k_place8, dim3(2048), dim3(256), 0, stream,
                     ei, offs, rank, csr, E, N);

  hipLaunchKernelGGL(k_agg, dim3(4096), dim3(256), 0, stream,
                     offs, deg, csr, (const float4*)a_src, (const float4*)a_dst, hb, out, N);
}

// Round 18
// 189.890 us; speedup vs baseline: 1.2294x; 1.0342x over previous
//
#include <hip/hip_runtime.h>

// GAT layer, CSR + single-pass softmax + MFMA linear. N=100000, E=1.6M, DIN=128, H=4, D=16.
// ROUND 18 = R17 + hist_rank FUSED back into k_linear's tail (R13-R16-proven
// fusion: atomic latency hides under GEMM memory phases across waves).
// rank[e] = atomicAdd(&deg[s],1) is the only atomic in the pipeline.

#define DIN 128
#define HD  64
#define NH  4
#define BTP 136

typedef __attribute__((ext_vector_type(8))) short short8;
typedef __attribute__((ext_vector_type(4))) float f32x4;

__device__ __forceinline__ float leaky02(float v) { return v > 0.f ? v : 0.2f * v; }

__device__ __forceinline__ float bf2f(unsigned short u) {
  union { unsigned u32; float f; } c; c.u32 = ((unsigned)u) << 16; return c.f;
}
__device__ __forceinline__ unsigned short f2bf(float f) {
  union { float f; unsigned u; } c; c.f = f;
  unsigned r = c.u + 0x7FFFu + ((c.u >> 16) & 1u);  // RNE
  return (unsigned short)(r >> 16);
}
__device__ __forceinline__ unsigned cvt_pk_bf16(float lo, float hi) {
  unsigned r;
  asm("v_cvt_pk_bf16_f32 %0, %1, %2" : "=v"(r) : "v"(lo), "v"(hi));
  return r;  // low16 = bf16(lo), high16 = bf16(hi)
}

// ---------------- K0: build pre-transposed bf16 fragment table ----------------
__global__ void k_wprep(const float* __restrict__ Wlin, const float* __restrict__ Watt,
                        unsigned short* __restrict__ btg) {
  for (int i = threadIdx.x; i < 80 * BTP; i += 256) {
    const int c = i / BTP, k = i % BTP;
    unsigned short v = 0;
    if (k < DIN) {
      if (c < 64) {
        v = f2bf(Wlin[k * HD + c]);
      } else if (c < 72) {
        const int cc = c - 64;
        const int head = cc & 3, dsth = (cc >= 4) ? 16 : 0;
        float s = 0.f;
#pragma unroll
        for (int d = 0; d < 16; ++d)
          s += Wlin[k * HD + head * 16 + d] * Watt[head * 32 + dsth + d];
        v = f2bf(s);
      }
    }
    btg[i] = v;
  }
}

// ---------------- K1: MFMA linear + fused hist_rank ----------------
// Block: 512 thr (8 waves), 128 rows (8 waves x 16 rows). Blessed geometry.
__global__ __launch_bounds__(512)
void k_linear(const float* __restrict__ x,
              const unsigned short* __restrict__ btg,
              unsigned short* __restrict__ hb,
              float* __restrict__ a_src, float* __restrict__ a_dst,
              int N,
              const int* __restrict__ ei, int* __restrict__ deg,
              int* __restrict__ rank, int E) {
  __shared__ __align__(16) unsigned short OT[8][16 * 68]; // 17 KiB C-staging (pad 68)
  __shared__ __align__(16) float AT[8][16 * 8];           // 4 KiB att-staging
  const int tid = threadIdx.x;
  const int lane = tid & 63;
  const int wid  = tid >> 6;  // 0..7

  const int row0 = blockIdx.x * 128 + wid * 16;
  const bool rowok = row0 < N;

  if (rowok) {
    // x loads first: HBM latency overlaps fragment loads
    float4 xv[8];
    {
      const int r = min(row0 + (lane & 15), N - 1);
      const float* xp = x + (size_t)r * DIN + ((lane >> 4) * 8);
#pragma unroll
      for (int kt = 0; kt < 4; ++kt) {
        xv[kt * 2 + 0] = *(const float4*)(xp + kt * 32);
        xv[kt * 2 + 1] = *(const float4*)(xp + kt * 32 + 4);
      }
    }

    // B fragments direct from global (21.76 KB table, L1-resident per CU)
    short8 bf[5][4];
#pragma unroll
    for (int ct = 0; ct < 5; ++ct) {
      const int c = (ct < 4) ? (ct * 16 + (lane & 15)) : (64 + (lane & 15));
#pragma unroll
      for (int kt = 0; kt < 4; ++kt)
        bf[ct][kt] = *(const short8*)(&btg[c * BTP + kt * 32 + (lane >> 4) * 8]);
    }

    short8 af[4];
#pragma unroll
    for (int kt = 0; kt < 4; ++kt) {
      unsigned* ap = (unsigned*)&af[kt];
      const float4 a = xv[kt * 2], b = xv[kt * 2 + 1];
      ap[0] = cvt_pk_bf16(a.x, a.y);
      ap[1] = cvt_pk_bf16(a.z, a.w);
      ap[2] = cvt_pk_bf16(b.x, b.y);
      ap[3] = cvt_pk_bf16(b.z, b.w);
    }
    f32x4 acc[5] = {{0,0,0,0},{0,0,0,0},{0,0,0,0},{0,0,0,0},{0,0,0,0}};
#pragma unroll
    for (int ct = 0; ct < 5; ++ct)
#pragma unroll
      for (int kt = 0; kt < 4; ++kt)
        acc[ct] = __builtin_amdgcn_mfma_f32_16x16x32_bf16(af[kt], bf[ct][kt], acc[ct], 0, 0, 0);

    // --- LDS-staged epilogue (wave-private, no barrier) ---
    // C/D layout: col = lane&15, row = (lane>>4)*4 + j
    const int c0 = lane & 15;
    const int r0 = (lane >> 4) * 4;
#pragma unroll
    for (int j = 0; j < 4; ++j) {
#pragma unroll
      for (int ct = 0; ct < 4; ++ct)
        OT[wid][(r0 + j) * 68 + ct * 16 + c0] = f2bf(acc[ct][j]);
      if (c0 < 8) AT[wid][(r0 + j) * 8 + c0] = acc[4][j];
    }
    // coalesced writeback: 2 rows (256B) per instruction
    unsigned* hbu = (unsigned*)(hb + (size_t)row0 * HD);
#pragma unroll
    for (int it = 0; it < 8; ++it) {
      const int rr = it * 2 + (lane >> 5);
      const int cw = lane & 31;
      const unsigned v = *(const unsigned*)&OT[wid][rr * 68 + cw * 2];
      if (row0 + rr < N) hbu[rr * 32 + cw] = v;
    }
    {
      const int rr = lane >> 2, cc = lane & 3;
      if (row0 + rr < N) {
        a_src[(row0 + rr) * 4 + cc] = AT[wid][rr * 8 + cc];
        a_dst[(row0 + rr) * 4 + cc] = AT[wid][rr * 8 + 4 + cc];
      }
    }
  }

  // fused hist + rank over this block's edge slice (atomic latency hides
  // under other waves' GEMM memory phases)
  const int per = (E + gridDim.x - 1) / gridDim.x;
  const int e0 = blockIdx.x * per;
  const int e1 = min(e0 + per, E);
  for (int e = e0 + tid; e < e1; e += 512)
    rank[e] = atomicAdd(&deg[ei[e]], 1);
}

// ---------------- K3a: per-block exclusive scan ----------------
__global__ void k_scanA(const int* __restrict__ deg, int* __restrict__ offs,
                        int* __restrict__ partials, int N) {
  __shared__ int wsum[16];
  const int tid = threadIdx.x, lane = tid & 63, wv = tid >> 6;
  int i = blockIdx.x * 1024 + tid;
  int v = (i < N) ? deg[i] : 0;
  int sc = v;
#pragma unroll
  for (int s = 1; s < 64; s <<= 1) {
    int t = __shfl_up(sc, s, 64);
    if (lane >= s) sc += t;
  }
  if (lane == 63) wsum[wv] = sc;
  __syncthreads();
  if (wv == 0 && lane < 16) {
    int w = wsum[lane];
    int s2 = w;
#pragma unroll
    for (int s = 1; s < 16; s <<= 1) {
      int t = __shfl_up(s2, s, 64);
      if (lane >= s) s2 += t;
    }
    wsum[lane] = s2 - w;
  }
  __syncthreads();
  int excl = sc - v + wsum[wv];
  if (i < N) offs[i] = excl;
  if (tid == 1023) partials[blockIdx.x] = excl + v;
}

// ---------------- K3b: add block bases ----------------
__global__ void k_scanB(int* __restrict__ offs, const int* __restrict__ partials, int N) {
  __shared__ int sbase;
  const int tid = threadIdx.x, b = blockIdx.x;
  if (tid < 64) {
    int acc = 0;
    for (int j = tid; j < b; j += 64) acc += partials[j];
#pragma unroll
    for (int s = 32; s >= 1; s >>= 1) acc += __shfl_xor(acc, s, 64);
    if (tid == 0) sbase = acc;
  }
  __syncthreads();
  int i = b * 1024 + tid;
  if (i < N) offs[i] += sbase;
}

// ---------------- K4: atomic-free placement, XCD-bucketed ----------------
__global__ void k_place8(const int* __restrict__ ei, const int* __restrict__ offs,
                         const int* __restrict__ rank, int* __restrict__ csr,
                         int E, int N) {
  const int xcd  = blockIdx.x & 7;
  const int grp  = blockIdx.x >> 3;
  const int ngrp = gridDim.x >> 3;
  const int step = (N + 7) >> 3;
  const int lo = xcd * step, hi = min(N, lo + step);
  const int stride = ngrp * blockDim.x;
  for (int e = grp * blockDim.x + threadIdx.x; e < E; e += stride) {
    int s = ei[e];
    if (s >= lo && s < hi)
      csr[offs[s] + rank[e]] = ei[E + e];
  }
}

// ---------------- K5: aggregate (beg = start, end = beg + deg) ----------------
__global__ __launch_bounds__(256)
void k_agg(const int* __restrict__ offs_start, const int* __restrict__ deg,
           const int* __restrict__ csr, const float4* __restrict__ a_src4,
           const float4* __restrict__ a_dst4,
           const unsigned short* __restrict__ hb,
           float* __restrict__ out, int N) {
  __shared__ float als[4][64 * NH];
  const int lane = threadIdx.x & 63;
  const int wid  = threadIdx.x >> 6;
  const int hh = lane >> 4;
  const int wstride = gridDim.x * 4;

  for (int n0 = blockIdx.x * 4 + wid; n0 < N; n0 += wstride) {
    const int n   = __builtin_amdgcn_readfirstlane(n0);
    const int beg = __builtin_amdgcn_readfirstlane(offs_start[n]);
    const int dg  = __builtin_amdgcn_readfirstlane(deg[n]);
    const int end = beg + dg;
    const float4 asv = a_src4[n];

    float s0 = 0.f, s1 = 0.f, s2 = 0.f, s3 = 0.f;
    float acc0 = 0.f, acc1 = 0.f;
    for (int base = beg; base < end; base += 64) {
      const int cnt = __builtin_amdgcn_readfirstlane(min(64, end - base));
      const bool act = lane < cnt;
      const int d = csr[act ? base + lane : beg];
      const float4 ad = a_dst4[d];
      const float p0 = act ? __expf(leaky02(asv.x + ad.x)) : 0.f;
      const float p1 = act ? __expf(leaky02(asv.y + ad.y)) : 0.f;
      const float p2 = act ? __expf(leaky02(asv.z + ad.z)) : 0.f;
      const float p3 = act ? __expf(leaky02(asv.w + ad.w)) : 0.f;
      s0 += p0; s1 += p1; s2 += p2; s3 += p3;
      *(float4*)&als[wid][lane * 4] = make_float4(p0, p1, p2, p3);

      int j = 0;
      for (; j + 8 <= cnt; j += 8) {  // scalar row bases, 8 gathers in flight
        int dds[8];
#pragma unroll
        for (int u = 0; u < 8; ++u)
          dds[u] = __builtin_amdgcn_readfirstlane(csr[base + j + u]);
        float hv[8];
#pragma unroll
        for (int u = 0; u < 8; ++u) hv[u] = bf2f(hb[(size_t)dds[u] * HD + lane]);
#pragma unroll
        for (int u = 0; u < 8; ++u) {
          const float av = als[wid][(j + u) * 4 + hh];
          if (u & 1) acc1 = fmaf(av, hv[u], acc1);
          else       acc0 = fmaf(av, hv[u], acc0);
        }
      }
      for (; j < cnt; ++j) {
        const int dd_ = __builtin_amdgcn_readfirstlane(csr[base + j]);
        const float av = als[wid][j * 4 + hh];
        acc0 = fmaf(av, bf2f(hb[(size_t)dd_ * HD + lane]), acc0);
      }
    }
#pragma unroll
    for (int s = 1; s < 64; s <<= 1) {
      s0 += __shfl_xor(s0, s, 64); s1 += __shfl_xor(s1, s, 64);
      s2 += __shfl_xor(s2, s, 64); s3 += __shfl_xor(s3, s, 64);
    }
    const float sh = (hh == 0) ? s0 : (hh == 1) ? s1 : (hh == 2) ? s2 : s3;
    out[(size_t)n * HD + lane] = (acc0 + acc1) * (1.f / (sh + 1e-16f));
  }
}

extern "C" void kernel_launch(void* const* d_in, const int* in_sizes, int n_in,
                              void* d_out, int out_size, void* d_ws, size_t ws_size,
                              hipStream_t stream) {
  const float* x    = (const float*)d_in[0];
  const int*   ei   = (const int*)d_in[1];
  const float* Wlin = (const float*)d_in[2];
  const float* Watt = (const float*)d_in[3];
  float* out = (float*)d_out;

  const int N = in_sizes[0] / DIN;
  const int E = in_sizes[1] / 2;

  char* ws = (char*)d_ws;
  size_t off = 0;
  auto align16 = [&off]() { off = (off + 15) & ~(size_t)15; };
  unsigned short* hb = (unsigned short*)(ws + off); off += (size_t)N * HD * sizeof(unsigned short); align16();
  float* a_src  = (float*)(ws + off); off += (size_t)N * NH * sizeof(float); align16();
  float* a_dst  = (float*)(ws + off); off += (size_t)N * NH * sizeof(float); align16();
  int*   deg    = (int*)(ws + off);   off += (size_t)N * sizeof(int); align16();
  int*   offs   = (int*)(ws + off);   off += ((size_t)N + 1) * sizeof(int); align16();
  int*   csr    = (int*)(ws + off);   off += (size_t)E * sizeof(int); align16();
  int*   rank   = (int*)(ws + off);   off += (size_t)E * sizeof(int); align16();
  int*   parts  = (int*)(ws + off);   off += 128 * sizeof(int); align16();
  unsigned short* btg = (unsigned short*)(ws + off); off += 80 * BTP * sizeof(unsigned short); align16();

  hipMemsetAsync(deg, 0, (size_t)N * sizeof(int), stream);

  hipLaunchKernelGGL(k_wprep, dim3(1), dim3(256), 0, stream, Wlin, Watt, btg);

  hipLaunchKernelGGL(k_linear, dim3((N + 127) / 128), dim3(512), 0, stream,
                     x, btg, hb, a_src, a_dst, N, ei, deg, rank, E);

  const int SB = (N + 1023) / 1024;
  hipLaunchKernelGGL(k_scanA, dim3(SB), dim3(1024), 0, stream, deg, offs, parts, N);
  hipLaunchKernelGGL(k_scanB, dim3(SB), dim3(1024), 0, stream, offs, parts, N);

  hipLaunchKernelGGL(k_place8, dim3(2048), dim3(256), 0, stream,
                     ei, offs, rank, csr, E, N);

  hipLaunchKernelGGL(k_agg, dim3(4096), dim3(256), 0, stream,
                     offs, deg, csr, (const float4*)a_src, (const float4*)a_dst, hb, out, N);
}

// Round 19
// 143.708 us; speedup vs baseline: 1.6245x; 1.3214x over previous
//
#include <hip/hip_runtime.h>

// GAT layer. N=100000, E=1.6M, DIN=128, H=4, D=16.
// ROUND 19 = ZERO global atomics. CSR built by two-level LDS counting sort:
//   P1: per-block LDS hist over 196 coarse buckets (s>>9) -> bhistT
//   scanA/B (proven) over 196*1024 cells -> sbase
//   P3: replay, LDS-atomic in-cell rank, scatter packed (s,d) -> tmp (bucketed)
//   P4: block per bucket: LDS hist/scan -> deg, offs, csr (contiguous window)
// k_linear = R17 pure-GEMM verbatim; k_agg verbatim; memset(deg) deleted.

#define DIN 128
#define HD  64
#define NH  4
#define BTP 136
#define NB  1024          // P1/P3 edge-slice blocks
#define BSH 9             // bucket = s >> 9 (512 src values per bucket)

typedef __attribute__((ext_vector_type(8))) short short8;
typedef __attribute__((ext_vector_type(4))) float f32x4;

__device__ __forceinline__ float leaky02(float v) { return v > 0.f ? v : 0.2f * v; }

__device__ __forceinline__ float bf2f(unsigned short u) {
  union { unsigned u32; float f; } c; c.u32 = ((unsigned)u) << 16; return c.f;
}
__device__ __forceinline__ unsigned short f2bf(float f) {
  union { float f; unsigned u; } c; c.f = f;
  unsigned r = c.u + 0x7FFFu + ((c.u >> 16) & 1u);  // RNE
  return (unsigned short)(r >> 16);
}
__device__ __forceinline__ unsigned cvt_pk_bf16(float lo, float hi) {
  unsigned r;
  asm("v_cvt_pk_bf16_f32 %0, %1, %2" : "=v"(r) : "v"(lo), "v"(hi));
  return r;
}

// ---------------- K0: build pre-transposed bf16 fragment table ----------------
__global__ void k_wprep(const float* __restrict__ Wlin, const float* __restrict__ Watt,
                        unsigned short* __restrict__ btg) {
  for (int i = threadIdx.x; i < 80 * BTP; i += 256) {
    const int c = i / BTP, k = i % BTP;
    unsigned short v = 0;
    if (k < DIN) {
      if (c < 64) {
        v = f2bf(Wlin[k * HD + c]);
      } else if (c < 72) {
        const int cc = c - 64;
        const int head = cc & 3, dsth = (cc >= 4) ? 16 : 0;
        float s = 0.f;
#pragma unroll
        for (int d = 0; d < 16; ++d)
          s += Wlin[k * HD + head * 16 + d] * Watt[head * 32 + dsth + d];
        v = f2bf(s);
      }
    }
    btg[i] = v;
  }
}

// ---------------- K1: MFMA linear, pure GEMM (R17 verbatim) ----------------
__global__ __launch_bounds__(512)
void k_linear(const float* __restrict__ x,
              const unsigned short* __restrict__ btg,
              unsigned short* __restrict__ hb,
              float* __restrict__ a_src, float* __restrict__ a_dst,
              int N) {
  __shared__ __align__(16) unsigned short OT[8][16 * 68];
  __shared__ __align__(16) float AT[8][16 * 8];
  const int tid = threadIdx.x;
  const int lane = tid & 63;
  const int wid  = tid >> 6;

  const int row0 = blockIdx.x * 128 + wid * 16;
  if (row0 >= N) return;

  float4 xv[8];
  {
    const int r = min(row0 + (lane & 15), N - 1);
    const float* xp = x + (size_t)r * DIN + ((lane >> 4) * 8);
#pragma unroll
    for (int kt = 0; kt < 4; ++kt) {
      xv[kt * 2 + 0] = *(const float4*)(xp + kt * 32);
      xv[kt * 2 + 1] = *(const float4*)(xp + kt * 32 + 4);
    }
  }

  short8 bf[5][4];
#pragma unroll
  for (int ct = 0; ct < 5; ++ct) {
    const int c = (ct < 4) ? (ct * 16 + (lane & 15)) : (64 + (lane & 15));
#pragma unroll
    for (int kt = 0; kt < 4; ++kt)
      bf[ct][kt] = *(const short8*)(&btg[c * BTP + kt * 32 + (lane >> 4) * 8]);
  }

  short8 af[4];
#pragma unroll
  for (int kt = 0; kt < 4; ++kt) {
    unsigned* ap = (unsigned*)&af[kt];
    const float4 a = xv[kt * 2], b = xv[kt * 2 + 1];
    ap[0] = cvt_pk_bf16(a.x, a.y);
    ap[1] = cvt_pk_bf16(a.z, a.w);
    ap[2] = cvt_pk_bf16(b.x, b.y);
    ap[3] = cvt_pk_bf16(b.z, b.w);
  }
  f32x4 acc[5] = {{0,0,0,0},{0,0,0,0},{0,0,0,0},{0,0,0,0},{0,0,0,0}};
#pragma unroll
  for (int ct = 0; ct < 5; ++ct)
#pragma unroll
    for (int kt = 0; kt < 4; ++kt)
      acc[ct] = __builtin_amdgcn_mfma_f32_16x16x32_bf16(af[kt], bf[ct][kt], acc[ct], 0, 0, 0);

  const int c0 = lane & 15;
  const int r0 = (lane >> 4) * 4;
#pragma unroll
  for (int j = 0; j < 4; ++j) {
#pragma unroll
    for (int ct = 0; ct < 4; ++ct)
      OT[wid][(r0 + j) * 68 + ct * 16 + c0] = f2bf(acc[ct][j]);
    if (c0 < 8) AT[wid][(r0 + j) * 8 + c0] = acc[4][j];
  }
  unsigned* hbu = (unsigned*)(hb + (size_t)row0 * HD);
#pragma unroll
  for (int it = 0; it < 8; ++it) {
    const int rr = it * 2 + (lane >> 5);
    const int cw = lane & 31;
    const unsigned v = *(const unsigned*)&OT[wid][rr * 68 + cw * 2];
    if (row0 + rr < N) hbu[rr * 32 + cw] = v;
  }
  {
    const int rr = lane >> 2, cc = lane & 3;
    if (row0 + rr < N) {
      a_src[(row0 + rr) * 4 + cc] = AT[wid][rr * 8 + cc];
      a_dst[(row0 + rr) * 4 + cc] = AT[wid][rr * 8 + 4 + cc];
    }
  }
}

// ---------------- P1: per-block coarse-bucket LDS histogram ----------------
__global__ __launch_bounds__(256)
void k_p1(const int* __restrict__ ei, int* __restrict__ bhistT, int E, int B) {
  __shared__ unsigned lh[256];
  const int tid = threadIdx.x, blk = blockIdx.x;
  lh[tid] = 0;
  __syncthreads();
  const int per = (E + NB - 1) / NB;
  const int e0 = blk * per, e1 = min(e0 + per, E);
  for (int e = e0 + tid; e < e1; e += 256)
    atomicAdd(&lh[ei[e] >> BSH], 1u);
  __syncthreads();
  if (tid < B) bhistT[tid * NB + blk] = (int)lh[tid];
}

// ---------------- K3a/K3b: exclusive scan (proven code) ----------------
__global__ void k_scanA(const int* __restrict__ deg, int* __restrict__ offs,
                        int* __restrict__ partials, int N) {
  __shared__ int wsum[16];
  const int tid = threadIdx.x, lane = tid & 63, wv = tid >> 6;
  int i = blockIdx.x * 1024 + tid;
  int v = (i < N) ? deg[i] : 0;
  int sc = v;
#pragma unroll
  for (int s = 1; s < 64; s <<= 1) {
    int t = __shfl_up(sc, s, 64);
    if (lane >= s) sc += t;
  }
  if (lane == 63) wsum[wv] = sc;
  __syncthreads();
  if (wv == 0 && lane < 16) {
    int w = wsum[lane];
    int s2 = w;
#pragma unroll
    for (int s = 1; s < 16; s <<= 1) {
      int t = __shfl_up(s2, s, 64);
      if (lane >= s) s2 += t;
    }
    wsum[lane] = s2 - w;
  }
  __syncthreads();
  int excl = sc - v + wsum[wv];
  if (i < N) offs[i] = excl;
  if (tid == 1023) partials[blockIdx.x] = excl + v;
}

__global__ void k_scanB(int* __restrict__ offs, const int* __restrict__ partials, int N) {
  __shared__ int sbase;
  const int tid = threadIdx.x, b = blockIdx.x;
  if (tid < 64) {
    int acc = 0;
    for (int j = tid; j < b; j += 64) acc += partials[j];
#pragma unroll
    for (int s = 32; s >= 1; s >>= 1) acc += __shfl_xor(acc, s, 64);
    if (tid == 0) sbase = acc;
  }
  __syncthreads();
  int i = b * 1024 + tid;
  if (i < N) offs[i] += sbase;
}

// ---------------- P3: bucket-partition edges (no global atomics) ----------------
__global__ __launch_bounds__(256)
void k_p3(const int* __restrict__ ei, const int* __restrict__ sbase,
          unsigned long long* __restrict__ tmp, int E) {
  __shared__ unsigned lh[256];
  const int tid = threadIdx.x, blk = blockIdx.x;
  lh[tid] = 0;
  __syncthreads();
  const int per = (E + NB - 1) / NB;
  const int e0 = blk * per, e1 = min(e0 + per, E);
  for (int e = e0 + tid; e < e1; e += 256) {
    const int s = ei[e];
    const int d = ei[E + e];
    const int b = s >> BSH;
    const unsigned lr = atomicAdd(&lh[b], 1u);   // in-cell rank (any permutation ok)
    const int pos = sbase[b * NB + blk] + (int)lr;
    tmp[pos] = ((unsigned long long)(unsigned)s << 32) | (unsigned)d;
  }
}

// ---------------- P4: per-bucket fine counting sort -> deg, offs, csr ----------------
__global__ __launch_bounds__(256)
void k_p4(const unsigned long long* __restrict__ tmp, const int* __restrict__ sbase,
          int* __restrict__ deg, int* __restrict__ offs, int* __restrict__ csr,
          int E, int N, int B) {
  __shared__ unsigned lh[512];
  __shared__ unsigned ex[512];
  __shared__ unsigned run[512];
  const int tid = threadIdx.x, b = blockIdx.x;
  const int lo = b << BSH;
  const int start = sbase[b * NB];
  const int end = (b + 1 < B) ? sbase[(b + 1) * NB] : E;

  lh[tid] = 0; lh[tid + 256] = 0;
  __syncthreads();
  for (int i = start + tid; i < end; i += 256)
    atomicAdd(&lh[(unsigned)(tmp[i] >> 32) - lo], 1u);
  __syncthreads();

  // exclusive scan of lh[0..511] by wave 0
  if (tid < 64) {
    const int lane = tid;
    unsigned carry = 0;
#pragma unroll
    for (int c = 0; c < 8; ++c) {
      unsigned v = lh[c * 64 + lane];
      unsigned sc = v;
#pragma unroll
      for (int sft = 1; sft < 64; sft <<= 1) {
        unsigned t = __shfl_up(sc, sft, 64);
        if (lane >= sft) sc += t;
      }
      ex[c * 64 + lane] = sc - v + carry;
      carry += __shfl(sc, 63, 64);
    }
  }
  __syncthreads();

  for (int i = tid; i < 512; i += 256) {
    const int n = lo + i;
    if (n < N) {
      deg[n]  = (int)lh[i];
      offs[n] = start + (int)ex[i];
    }
    run[i] = ex[i];
  }
  __syncthreads();

  for (int i = start + tid; i < end; i += 256) {
    const unsigned long long p = tmp[i];
    const unsigned s = (unsigned)(p >> 32);
    const unsigned r = atomicAdd(&run[s - lo], 1u);
    csr[start + (int)r] = (int)(unsigned)p;
  }
}

// ---------------- K5: aggregate (R17/R18 verbatim) ----------------
__global__ __launch_bounds__(256)
void k_agg(const int* __restrict__ offs_start, const int* __restrict__ deg,
           const int* __restrict__ csr, const float4* __restrict__ a_src4,
           const float4* __restrict__ a_dst4,
           const unsigned short* __restrict__ hb,
           float* __restrict__ out, int N) {
  __shared__ float als[4][64 * NH];
  const int lane = threadIdx.x & 63;
  const int wid  = threadIdx.x >> 6;
  const int hh = lane >> 4;
  const int wstride = gridDim.x * 4;

  for (int n0 = blockIdx.x * 4 + wid; n0 < N; n0 += wstride) {
    const int n   = __builtin_amdgcn_readfirstlane(n0);
    const int beg = __builtin_amdgcn_readfirstlane(offs_start[n]);
    const int dg  = __builtin_amdgcn_readfirstlane(deg[n]);
    const int end = beg + dg;
    const float4 asv = a_src4[n];

    float s0 = 0.f, s1 = 0.f, s2 = 0.f, s3 = 0.f;
    float acc0 = 0.f, acc1 = 0.f;
    for (int base = beg; base < end; base += 64) {
      const int cnt = __builtin_amdgcn_readfirstlane(min(64, end - base));
      const bool act = lane < cnt;
      const int d = csr[act ? base + lane : beg];
      const float4 ad = a_dst4[d];
      const float p0 = act ? __expf(leaky02(asv.x + ad.x)) : 0.f;
      const float p1 = act ? __expf(leaky02(asv.y + ad.y)) : 0.f;
      const float p2 = act ? __expf(leaky02(asv.z + ad.z)) : 0.f;
      const float p3 = act ? __expf(leaky02(asv.w + ad.w)) : 0.f;
      s0 += p0; s1 += p1; s2 += p2; s3 += p3;
      *(float4*)&als[wid][lane * 4] = make_float4(p0, p1, p2, p3);

      int j = 0;
      for (; j + 8 <= cnt; j += 8) {
        int dds[8];
#pragma unroll
        for (int u = 0; u < 8; ++u)
          dds[u] = __builtin_amdgcn_readfirstlane(csr[base + j + u]);
        float hv[8];
#pragma unroll
        for (int u = 0; u < 8; ++u) hv[u] = bf2f(hb[(size_t)dds[u] * HD + lane]);
#pragma unroll
        for (int u = 0; u < 8; ++u) {
          const float av = als[wid][(j + u) * 4 + hh];
          if (u & 1) acc1 = fmaf(av, hv[u], acc1);
          else       acc0 = fmaf(av, hv[u], acc0);
        }
      }
      for (; j < cnt; ++j) {
        const int dd_ = __builtin_amdgcn_readfirstlane(csr[base + j]);
        const float av = als[wid][j * 4 + hh];
        acc0 = fmaf(av, bf2f(hb[(size_t)dd_ * HD + lane]), acc0);
      }
    }
#pragma unroll
    for (int s = 1; s < 64; s <<= 1) {
      s0 += __shfl_xor(s0, s, 64); s1 += __shfl_xor(s1, s, 64);
      s2 += __shfl_xor(s2, s, 64); s3 += __shfl_xor(s3, s, 64);
    }
    const float sh = (hh == 0) ? s0 : (hh == 1) ? s1 : (hh == 2) ? s2 : s3;
    out[(size_t)n * HD + lane] = (acc0 + acc1) * (1.f / (sh + 1e-16f));
  }
}

extern "C" void kernel_launch(void* const* d_in, const int* in_sizes, int n_in,
                              void* d_out, int out_size, void* d_ws, size_t ws_size,
                              hipStream_t stream) {
  const float* x    = (const float*)d_in[0];
  const int*   ei   = (const int*)d_in[1];
  const float* Wlin = (const float*)d_in[2];
  const float* Watt = (const float*)d_in[3];
  float* out = (float*)d_out;

  const int N = in_sizes[0] / DIN;
  const int E = in_sizes[1] / 2;
  const int B = (N + (1 << BSH) - 1) >> BSH;   // 196 buckets
  const int M = B * NB;                         // scan length

  char* ws = (char*)d_ws;
  size_t off = 0;
  auto align16 = [&off]() { off = (off + 15) & ~(size_t)15; };
  unsigned short* hb = (unsigned short*)(ws + off); off += (size_t)N * HD * sizeof(unsigned short); align16();
  float* a_src  = (float*)(ws + off); off += (size_t)N * NH * sizeof(float); align16();
  float* a_dst  = (float*)(ws + off); off += (size_t)N * NH * sizeof(float); align16();
  int*   deg    = (int*)(ws + off);   off += (size_t)N * sizeof(int); align16();
  int*   offs   = (int*)(ws + off);   off += ((size_t)N + 1) * sizeof(int); align16();
  int*   csr    = (int*)(ws + off);   off += (size_t)E * sizeof(int); align16();
  unsigned long long* tmp = (unsigned long long*)(ws + off); off += (size_t)E * sizeof(unsigned long long); align16();
  int*   bhistT = (int*)(ws + off);   off += (size_t)M * sizeof(int); align16();
  int*   sbase  = (int*)(ws + off);   off += (size_t)M * sizeof(int); align16();
  int*   parts  = (int*)(ws + off);   off += 256 * sizeof(int); align16();
  unsigned short* btg = (unsigned short*)(ws + off); off += 80 * BTP * sizeof(unsigned short); align16();

  hipLaunchKernelGGL(k_wprep, dim3(1), dim3(256), 0, stream, Wlin, Watt, btg);

  hipLaunchKernelGGL(k_linear, dim3((N + 127) / 128), dim3(512), 0, stream,
                     x, btg, hb, a_src, a_dst, N);

  hipLaunchKernelGGL(k_p1, dim3(NB), dim3(256), 0, stream, ei, bhistT, E, B);

  const int SB = (M + 1023) / 1024;  // == B
  hipLaunchKernelGGL(k_scanA, dim3(SB), dim3(1024), 0, stream, bhistT, sbase, parts, M);
  hipLaunchKernelGGL(k_scanB, dim3(SB), dim3(1024), 0, stream, sbase, parts, M);

  hipLaunchKernelGGL(k_p3, dim3(NB), dim3(256), 0, stream, ei, sbase, tmp, E);

  hipLaunchKernelGGL(k_p4, dim3(B), dim3(256), 0, stream,
                     tmp, sbase, deg, offs, csr, E, N, B);

  hipLaunchKernelGGL(k_agg, dim3(4096), dim3(256), 0, stream,
                     offs, deg, csr, (const float4*)a_src, (const float4*)a_dst, hb, out, N);
}